// Round 6
// baseline (194.179 us; speedup 1.0000x reference)
//
#include <hip/hip_runtime.h>

#define NIMG 64
#define H 512
#define W 512
#define HW (H * W)

typedef float f4 __attribute__((ext_vector_type(4)));
typedef int   i4 __attribute__((ext_vector_type(4)));

constexpr float THR_64  = 50.0f / 255.0f;          // level_idx=1: 64x64 details
constexpr float THR_128 = 50.0f / 2.0f / 255.0f;   // level_idx=2: 128x128
constexpr float THR_256 = 50.0f / 4.0f / 255.0f;   // level_idx=3: 256x256

constexpr float SC_W1 = 0.2f  / 37748736.0f;
constexpr float SC_W2 = 0.2f  / 6291456.0f;
constexpr float SC_W3 = 0.2f  / 786432.0f;
constexpr float SC_TV = 0.01f / 16744448.0f;

__device__ __forceinline__ float wave_sum(float v) {
#pragma unroll
    for (int o = 32; o > 0; o >>= 1) v += __shfl_down(v, o, 64);
    return v;
}

__device__ __forceinline__ float clip01(float x) {
    return fminf(fmaxf(x, 0.0f), 1.0f);
}

__device__ __forceinline__ f4 clip4(f4 p) {
    p.x = clip01(p.x); p.y = clip01(p.y); p.z = clip01(p.z); p.w = clip01(p.w);
    return p;
}

// Kernel A (rolled streaming): wave owns an 8-row x 256-col half-slab and
// processes it in FOUR rolled 2-row iterations (#pragma unroll 1) -> the wave
// issues loads continuously over its whole life (copy-kernel shape) instead
// of one burst. Carried state is tiny (prev row, 2 LL1, 2 LL2 scalars), so
// VGPR stays low and all 8192 waves are near-fully resident in one dispatch
// generation. No LDS, no __syncthreads; wave self-reduces to pOut[gw].
// Math is identical to the verified round-3/5 kernel (absmax 0).
__global__ __launch_bounds__(256, 4) void kA(const float* __restrict__ pred,
                                             const float* __restrict__ noisy,
                                             const int* __restrict__ mask,
                                             f4* __restrict__ pOut) {
    const int tid = threadIdx.x;
    const int lane = tid & 63;
    const int wv = tid >> 6;
    const int gw = (blockIdx.x << 2) + wv;   // global wave id, 0..8191
    const int n = gw >> 7;                   // image (128 waves per image)
    const int u = gw & 127;
    const int s = u >> 1;                    // slab (8 rows)
    const int h = u & 1;                     // column half
    const int r0 = s << 3;                   // first global row
    const int col0 = (h << 8) + (lane << 2); // this lane's first column
    const size_t img = (size_t)n * HW;
    const size_t base = img + (size_t)r0 * W + col0;

    const float* pb = pred + base;
    const float* nb = noisy + base;
    const int*   mb = mask + base;

    // seam col 256 for rows r0..r0+7 (lanes 0..7 hold one row each)
    float smv = 0.f;
    if (h == 0 && lane < 8)
        smv = pred[img + (size_t)(r0 + lane) * W + 256];
    smv = clip01(smv);

    // vertical halo row (r0-1) -> becomes "prev" for iteration 0
    f4 prev = {0.f, 0.f, 0.f, 0.f};
    if (r0 > 0)
        prev = clip4(*reinterpret_cast<const f4*>(pb - W));

    float n2v = 0.f, msum = 0.f, tv = 0.f, wav1 = 0.f, wav2 = 0.f;
    float ll1pa = 0.f, ll1pb = 0.f;          // L1 outputs carried from even iter
    float ll2A = 0.f, ll2B = 0.f;            // L2 outputs from it==1 / it==3

#pragma unroll 1
    for (int it = 0; it < 4; ++it) {
        // ---- loads for this row pair ----
        const i4 m0 = *reinterpret_cast<const i4*>(mb);
        const i4 m1 = *reinterpret_cast<const i4*>(mb + W);
        f4 p0 = *reinterpret_cast<const f4*>(pb);
        f4 p1 = *reinterpret_cast<const f4*>(pb + W);
        f4 nz0 = {0.f, 0.f, 0.f, 0.f}, nz1 = {0.f, 0.f, 0.f, 0.f};
        if ((m0.x | m0.y | m0.z | m0.w) != 0)
            nz0 = *reinterpret_cast<const f4*>(nb);
        if ((m1.x | m1.y | m1.z | m1.w) != 0)
            nz1 = *reinterpret_cast<const f4*>(nb + W);
        pb += 2 * W; nb += 2 * W; mb += 2 * W;

        p0 = clip4(p0);
        p1 = clip4(p1);

        // ---- n2v ----
        {
            float mm;
            mm = m0.x ? 1.f : 0.f; n2v += fabsf(p0.x - nz0.x) * mm; msum += mm;
            mm = m0.y ? 1.f : 0.f; n2v += fabsf(p0.y - nz0.y) * mm; msum += mm;
            mm = m0.z ? 1.f : 0.f; n2v += fabsf(p0.z - nz0.z) * mm; msum += mm;
            mm = m0.w ? 1.f : 0.f; n2v += fabsf(p0.w - nz0.w) * mm; msum += mm;
            mm = m1.x ? 1.f : 0.f; n2v += fabsf(p1.x - nz1.x) * mm; msum += mm;
            mm = m1.y ? 1.f : 0.f; n2v += fabsf(p1.y - nz1.y) * mm; msum += mm;
            mm = m1.z ? 1.f : 0.f; n2v += fabsf(p1.z - nz1.z) * mm; msum += mm;
            mm = m1.w ? 1.f : 0.f; n2v += fabsf(p1.w - nz1.w) * mm; msum += mm;
        }

        // ---- TV horizontal (both rows) ----
        {
            const f4 q = p0;
            tv += fabsf(q.y - q.x) + fabsf(q.z - q.y) + fabsf(q.w - q.z);
            float nbx = __shfl_down(q.x, 1, 64);
            const float se = __shfl(smv, 2 * it, 64);
            if (lane == 63) nbx = se;
            if (lane < 63 || h == 0) tv += fabsf(nbx - q.w);
        }
        {
            const f4 q = p1;
            tv += fabsf(q.y - q.x) + fabsf(q.z - q.y) + fabsf(q.w - q.z);
            float nbx = __shfl_down(q.x, 1, 64);
            const float se = __shfl(smv, 2 * it + 1, 64);
            if (lane == 63) nbx = se;
            if (lane < 63 || h == 0) tv += fabsf(nbx - q.w);
        }

        // ---- TV vertical ----
        if (it + r0 > 0) {
            tv += fabsf(p0.x - prev.x) + fabsf(p0.y - prev.y)
                + fabsf(p0.z - prev.z) + fabsf(p0.w - prev.w);
        }
        tv += fabsf(p1.x - p0.x) + fabsf(p1.y - p0.y)
            + fabsf(p1.z - p0.z) + fabsf(p1.w - p0.w);
        prev = p1;

        // ---- Haar level 1 (2 quads) ----
        float a, b, c, d, ch, cv, cd;
        a = p0.x; b = p0.y; c = p1.x; d = p1.y;
        const float lla = (a + b + c + d) * 0.5f;
        ch = (a + b - c - d) * 0.5f; cv = (a - b + c - d) * 0.5f; cd = (a - b - c + d) * 0.5f;
        wav1 += fminf(fabsf(ch), THR_256) + fminf(fabsf(cv), THR_256) + fminf(fabsf(cd), THR_256);
        a = p0.z; b = p0.w; c = p1.z; d = p1.w;
        const float llb = (a + b + c + d) * 0.5f;
        ch = (a + b - c - d) * 0.5f; cv = (a - b + c - d) * 0.5f; cd = (a - b - c + d) * 0.5f;
        wav1 += fminf(fabsf(ch), THR_256) + fminf(fabsf(cv), THR_256) + fminf(fabsf(cd), THR_256);

        // ---- Haar level 2 (every second iteration) ----
        if (it & 1) {
            a = ll1pa; b = ll1pb; c = lla; d = llb;
            const float ll2v = (a + b + c + d) * 0.5f;
            ch = (a + b - c - d) * 0.5f;
            cv = (a - b + c - d) * 0.5f;
            cd = (a - b - c + d) * 0.5f;
            wav2 += fminf(fabsf(ch), THR_128) + fminf(fabsf(cv), THR_128) + fminf(fabsf(cd), THR_128);
            if (it == 1) ll2A = ll2v; else ll2B = ll2v;
        } else {
            ll1pa = lla; ll1pb = llb;
        }
    }

    // ---- Haar level 3 (lane-pair via shfl_xor; even lanes own quad) ----
    float w3 = 0.0f;
    {
        const float b3 = __shfl_xor(ll2A, 1, 64);
        const float d3 = __shfl_xor(ll2B, 1, 64);
        if ((lane & 1) == 0) {
            const float a = ll2A, b = b3, c = ll2B, d = d3;
            const float ch = (a + b - c - d) * 0.5f;
            const float cv = (a - b + c - d) * 0.5f;
            const float cd = (a - b - c + d) * 0.5f;
            w3 = fminf(fabsf(ch), THR_64) + fminf(fabsf(cv), THR_64)
               + fminf(fabsf(cd), THR_64);
        }
    }

    const float comb = wav1 * SC_W1 + wav2 * SC_W2 + w3 * SC_W3 + tv * SC_TV;

    // ---- wave-local reduction -> one float4 partial per wave ----
    float v0 = wave_sum(n2v);
    float v1 = wave_sum(msum);
    float v2 = wave_sum(comb);
    if (lane == 0) {
        f4 o = {v0, v1, v2, 0.f};
        pOut[gw] = o;
    }
}

// Kernel D: reduce 8192 float4 partials, compose final loss.
__global__ __launch_bounds__(256) void kD(const f4* __restrict__ pA,
                                          float* __restrict__ out) {
    __shared__ float red[4][3];
    const int tid = threadIdx.x;
    const int lane = tid & 63, wv = tid >> 6;

    float s0 = 0, s1 = 0, s2 = 0;
#pragma unroll
    for (int j = 0; j < 32; ++j) {
        f4 v = pA[tid + (j << 8)];
        s0 += v.x; s1 += v.y; s2 += v.z;
    }
    s0 = wave_sum(s0); s1 = wave_sum(s1); s2 = wave_sum(s2);
    if (lane == 0) {
        red[wv][0] = s0; red[wv][1] = s1; red[wv][2] = s2;
    }
    __syncthreads();
    if (tid == 0) {
        float a0 = red[0][0] + red[1][0] + red[2][0] + red[3][0];
        float a1 = red[0][1] + red[1][1] + red[2][1] + red[3][1];
        float a2 = red[0][2] + red[1][2] + red[2][2] + red[3][2];
        out[0] = a0 / fmaxf(a1, 1.0f) + a2;   // n2v + (0.2*wav + 0.01*tv)
    }
}

extern "C" void kernel_launch(void* const* d_in, const int* in_sizes, int n_in,
                              void* d_out, int out_size, void* d_ws, size_t ws_size,
                              hipStream_t stream) {
    (void)in_sizes; (void)n_in; (void)out_size; (void)ws_size;
    const float* pred  = (const float*)d_in[0];
    const float* noisy = (const float*)d_in[1];
    const int*   mask  = (const int*)d_in[2];

    f4* pA = (f4*)d_ws;                                   // 8192 * 16 B = 128 KB

    kA<<<2048, 256, 0, stream>>>(pred, noisy, mask, pA);
    kD<<<1, 256, 0, stream>>>(pA, (float*)d_out);
}